// Round 8
// baseline (331.552 us; speedup 1.0000x reference)
//
#include <hip/hip_runtime.h>

#define BATCH 16
#define CCH 512
#define LEN 4096
#define LPAD 4098

typedef unsigned short u16;
typedef __bf16 bf16x8 __attribute__((ext_vector_type(8)));
typedef float f32x4 __attribute__((ext_vector_type(4)));
typedef u16 u16x8 __attribute__((ext_vector_type(8)));
typedef u16 u16x4 __attribute__((ext_vector_type(4)));

__device__ __forceinline__ u16 f2bf(float f) {
    unsigned u = __float_as_uint(f);
    u = (u + 0x7fffu + ((u >> 16) & 1u)) >> 16;
    return (u16)u;
}
__device__ __forceinline__ float bf2f(u16 v) {
    return __uint_as_float(((unsigned)v) << 16);
}
__device__ __forceinline__ float silu_f(float v) {
    return v / (1.f + __expf(-v));
}
__device__ __forceinline__ void async16(const u16* g, u16* l) {
    __builtin_amdgcn_global_load_lds(
        (const __attribute__((address_space(1))) unsigned int*)g,
        (__attribute__((address_space(3))) unsigned int*)l, 16, 0, 0);
}

#define SBAR() __builtin_amdgcn_sched_barrier(0)
#define HWBAR() { SBAR(); __builtin_amdgcn_s_barrier(); SBAR(); }
#define WAIT_LGKM0() { asm volatile("s_waitcnt lgkmcnt(0)" ::: "memory"); SBAR(); }
#define WAIT_VM(n) { asm volatile("s_waitcnt vmcnt(" #n ")" ::: "memory"); SBAR(); }

// ---------------------------------------------------------------------------
__global__ __launch_bounds__(256)
void absmean_partial(const float* __restrict__ w1, const float* __restrict__ w2,
                     float* __restrict__ part) {
    const int tid = threadIdx.x;
    const int base = blockIdx.x * 3072;
    float s1 = 0.f, s2 = 0.f;
    for (int i = tid; i < 3072; i += 256) {
        s1 += fabsf(w1[base + i]);
        s2 += fabsf(w2[base + i]);
    }
    __shared__ float r1[256], r2[256];
    r1[tid] = s1; r2[tid] = s2;
    __syncthreads();
    for (int off = 128; off > 0; off >>= 1) {
        if (tid < off) { r1[tid] += r1[tid + off]; r2[tid] += r2[tid + off]; }
        __syncthreads();
    }
    if (tid == 0) { part[blockIdx.x] = r1[0]; part[256 + blockIdx.x] = r2[0]; }
}

__global__ __launch_bounds__(256)
void finalize_scale(const float* __restrict__ part, float* __restrict__ sv) {
    const int tid = threadIdx.x;
    __shared__ float r1[256], r2[256];
    r1[tid] = part[tid]; r2[tid] = part[256 + tid];
    __syncthreads();
    for (int off = 128; off > 0; off >>= 1) {
        if (tid < off) { r1[tid] += r1[tid + off]; r2[tid] += r2[tid + off]; }
        __syncthreads();
    }
    if (tid == 0) {
        sv[0] = fmaxf(r1[0] * (1.f / 786432.f), 1e-5f);
        sv[1] = fmaxf(r2[0] * (1.f / 786432.f), 1e-5f);
    }
}

// ---------------------------------------------------------------------------
__global__ __launch_bounds__(256)
void quantize_w(const float* __restrict__ w, const float* __restrict__ sv,
                int sidx, u16* __restrict__ wqt) {
    const int idx = blockIdx.x * 256 + threadIdx.x;
    const float s = sv[sidx];
    float q = rintf(w[idx] / s);
    q = fmaxf(-1.f, fminf(1.f, q));
    const int o   = idx / 1536;
    const int rem = idx - o * 1536;
    const int i   = rem / 3;
    const int k   = rem - i * 3;
    wqt[k * (CCH * CCH) + o * CCH + i] = f2bf(q);
}

__global__ __launch_bounds__(256)
void zero_pads(u16* __restrict__ h, u16* __restrict__ h1) {
    const int idx = blockIdx.x * 256 + threadIdx.x;   // [0, 16384)
    const int b = idx >> 10;
    const int r = (idx >> 9) & 1;
    const int i = idx & 511;
    const size_t off = ((size_t)b * LPAD + (r ? (LPAD - 1) : 0)) * CCH + i;
    h[off] = 0;
    h1[off] = 0;
}

// ---------------------------------------------------------------------------
__global__ __launch_bounds__(256)
void rms_silu_transpose(const float* __restrict__ x, const float* __restrict__ g,
                        u16* __restrict__ h_t) {
    __shared__ u16   xt[CCH][33];
    __shared__ float red[8][32];
    __shared__ float rinv[32];
    const int tid = threadIdx.x;
    const int bb  = blockIdx.x >> 7;
    const int l0  = (blockIdx.x & 127) << 5;

    const size_t xbase = (size_t)bb * CCH * LEN + l0;
    {
        const int i_hi = tid >> 3;
        const int l4   = (tid & 7) << 2;
        #pragma unroll
        for (int it = 0; it < 16; ++it) {
            const int i = it * 32 + i_hi;
            const float4 v = *(const float4*)&x[xbase + (size_t)i * LEN + l4];
            xt[i][l4 + 0] = f2bf(v.x);
            xt[i][l4 + 1] = f2bf(v.y);
            xt[i][l4 + 2] = f2bf(v.z);
            xt[i][l4 + 3] = f2bf(v.w);
        }
    }
    __syncthreads();
    {
        const int l = tid & 31, seg = tid >> 5;
        const int ibeg = seg * 64;
        float ss = 0.f;
        #pragma unroll 8
        for (int i = ibeg; i < ibeg + 64; ++i) {
            const float v = bf2f(xt[i][l]);
            ss += v * v;
        }
        red[seg][l] = ss;
    }
    __syncthreads();
    if (tid < 32) {
        float tot = 0.f;
        #pragma unroll
        for (int k2 = 0; k2 < 8; ++k2) tot += red[k2][tid];
        rinv[tid] = rsqrtf(tot * (1.f / 512.f) + 1e-6f);
    }
    __syncthreads();
    {
        const int l  = tid >> 3;
        const int i0 = (tid & 7) << 6;
        const float ri = rinv[l];
        const size_t ob = ((size_t)bb * LPAD + l0 + l + 1) * CCH + i0;
        for (int ii = 0; ii < 64; ii += 8) {
            u16x8 ov;
            #pragma unroll
            for (int jj = 0; jj < 8; ++jj) {
                const int i = i0 + ii + jj;
                float v = bf2f(xt[i][l]) * ri * g[i];
                ov[jj] = f2bf(silu_f(v));
            }
            *(u16x8*)&h_t[ob + ii] = ov;
        }
    }
}

// ---------------------------------------------------------------------------
// Conv-as-GEMM.  Block tile 256(o) x 128(l), BK=32, 256 threads = 4 waves
// (2M x 2N), per-wave 128x64 (8x4 16x16x32 frags, acc=128).  Triple-buffered
// LDS 72 KiB -> 2 blocks/CU = two desynchronized barrier domains.
// LDS layout per buf: A[256][32] + B[128][32] u16, NATURAL (no swizzle):
// at 64B row pitch the frag read (row=lane&15, colchunk=lane>>4) is
// bank-uniform (each bank serves exactly 8 words per ds_read_b128).
// Prefetch depth 2 with counted vmcnt(6).  K order ks-inner.
template<int EPI>
__global__ __launch_bounds__(256, 2)
void conv_gemm8(const u16* __restrict__ Bsrc, const u16* __restrict__ Wq,
                const float* __restrict__ sptr, const float* __restrict__ bias,
                const float* __restrict__ resid, u16* __restrict__ outb,
                float* __restrict__ outf) {
    extern __shared__ u16 lds[];          // 36864 u16 = 72 KiB (3 x 12288)
    const int tid  = threadIdx.x;
    const int lane = tid & 63;
    const int wave = tid >> 6;
    const int wm = wave >> 1;             // 0..1  (M half, 128 rows)
    const int wn = wave & 1;              // 0..1  (N half, 64 cols)

    // T1: bijective XCD chunking (1024 = 8 x 128); wgid-pairs share a B-panel.
    const int wgid = (blockIdx.x & 7) * 128 + (blockIdx.x >> 3);
    const int mt = wgid & 1;
    const int nt = wgid >> 1;             // 0..511
    const int o0 = mt << 8;               // 0 or 256
    const int bb = nt >> 5;               // 0..15
    const int l0 = (nt & 31) << 7;        // 0..3968

    // staging: round covers 64 rows; thread -> row (tid>>2), 16B chunk (tid&3)
    const u16* aSrcBase = Wq + (size_t)(o0 + (tid >> 2)) * CCH + ((tid & 3) << 3);
    const u16* bSrcBase = Bsrc + ((size_t)bb * LPAD + l0 + (tid >> 2)) * CCH +
                          ((tid & 3) << 3);
    const int sdst = tid << 3;            // u16; dst = row*32+(tid&3)*8 = tid*8

    // stage K-step t into buffer pb: A 256x32 (4 rounds) + B 128x32 (2 rounds)
    auto stage_full = [&](int pb, int t) {
        const int ks = t % 3;
        const int i0 = (t / 3) << 5;
        const u16* wsrc = aSrcBase + ks * (CCH * CCH) + i0;
        u16* const ad = &lds[pb * 12288 + sdst];
        #pragma unroll
        for (int j = 0; j < 4; ++j)
            async16(wsrc + j * 64 * CCH, ad + j * 2048);
        const u16* bsrc = bSrcBase + (size_t)ks * CCH + i0;
        u16* const bd = &lds[pb * 12288 + 8192 + sdst];
        #pragma unroll
        for (int j = 0; j < 2; ++j)
            async16(bsrc + (size_t)j * 64 * CCH, bd + j * 2048);
    };

    // frag reads (natural layout): row = lane&15 (+16 per frag), k = (lane>>4)*8
    const int co   = (lane >> 4) << 3;
    const int aOff = wm * 4096 + (lane & 15) * 32 + co;          // + m*512
    const int bOff = 8192 + wn * 2048 + (lane & 15) * 32 + co;   // + n*512

    f32x4 acc[8][4];
    #pragma unroll
    for (int m = 0; m < 8; ++m)
        #pragma unroll
        for (int n = 0; n < 4; ++n)
            acc[m][n] = (f32x4){0.f, 0.f, 0.f, 0.f};

    // prologue: t0 -> buf0, t1 -> buf1; wait for t0 (t1's 6 stay in flight)
    stage_full(0, 0);
    stage_full(1, 1);
    WAIT_VM(6);
    HWBAR();

    int pb = 0;
    for (int t = 0; t < 48; ++t) {
        const bool full = (t < 46);
        if (full) {
            int nb = pb + 2; if (nb >= 3) nb -= 3;
            stage_full(nb, t + 2);                 // prefetch depth 2
        }
        const int cb = pb * 12288;
        bf16x8 ar[8], br[4];
        #pragma unroll
        for (int m = 0; m < 8; ++m)
            ar[m] = *(const bf16x8*)&lds[cb + aOff + m * 512];
        #pragma unroll
        for (int n = 0; n < 4; ++n)
            br[n] = *(const bf16x8*)&lds[cb + bOff + n * 512];
        __builtin_amdgcn_s_setprio(1);
        #pragma unroll
        for (int m = 0; m < 8; ++m)
            #pragma unroll
            for (int n = 0; n < 4; ++n)
                acc[m][n] = __builtin_amdgcn_mfma_f32_16x16x32_bf16(
                    ar[m], br[n], acc[m][n], 0, 0, 0);
        __builtin_amdgcn_s_setprio(0);
        WAIT_LGKM0();                  // this buf's reads retired (WAR safety)
        if (full) { WAIT_VM(6); } else { WAIT_VM(0); }   // next buf landed
        HWBAR();
        ++pb; if (pb == 3) pb = 0;
    }

    // epilogue
    const float sc = sptr[0];

    if (EPI == 1) {
        // silu(sc*acc+bias) -> LDS [l_loc 0..127][o_loc 0..255] bf16 swizzled
        // (row pitch 512B), then coalesced 16B stores (4 lanes per 64B sector).
        #pragma unroll
        for (int m = 0; m < 8; ++m) {
            const int o_loc = wm * 128 + m * 16 + ((lane >> 4) << 2);
            const int ob = o0 + o_loc;
            const float b0 = bias[ob + 0], b1 = bias[ob + 1];
            const float b2 = bias[ob + 2], b3 = bias[ob + 3];
            #pragma unroll
            for (int n = 0; n < 4; ++n) {
                const int l_loc = wn * 64 + n * 16 + (lane & 15);
                const f32x4 a = acc[m][n];
                u16x4 ov;
                ov[0] = f2bf(silu_f(sc * a[0] + b0));
                ov[1] = f2bf(silu_f(sc * a[1] + b1));
                ov[2] = f2bf(silu_f(sc * a[2] + b2));
                ov[3] = f2bf(silu_f(sc * a[3] + b3));
                char* p = (char*)lds + l_loc * 512 +
                          (((unsigned)(o_loc << 1)) ^ ((l_loc & 7) << 4));
                *(u16x4*)p = ov;
            }
        }
        __syncthreads();
        const int oq = (tid & 3) << 3;       // u16: 0,8,16,24
        #pragma unroll
        for (int pass = 0; pass < 2; ++pass) {
            const int lr = (tid >> 2) + pass * 64;     // 0..127
            u16* gdst = outb + ((size_t)bb * LPAD + l0 + lr + 1) * CCH + o0 + oq;
            char* srp = (char*)lds + lr * 512;
            const int swz2 = (lr & 7) << 4;
            #pragma unroll
            for (int c = 0; c < 8; ++c) {
                const uint4 v = *(const uint4*)(srp + ((oq * 2 + c * 64) ^ swz2));
                *(uint4*)(gdst + c * 32) = v;
            }
        }
    } else {
        const int lbase = l0 + wn * 64 + (lane & 15);
        const int obase = o0 + wm * 128 + ((lane >> 4) << 2);
        #pragma unroll
        for (int m = 0; m < 8; ++m) {
            const int ob = obase + m * 16;
            #pragma unroll
            for (int n = 0; n < 4; ++n) {
                const int l = lbase + n * 16;
                const f32x4 a = acc[m][n];
                #pragma unroll
                for (int jj = 0; jj < 4; ++jj) {
                    const size_t idx = ((size_t)bb * CCH + (ob + jj)) * LEN + l;
                    outf[idx] = sc * a[jj] + bias[ob + jj] + resid[idx];
                }
            }
        }
    }
}

// ---------------------------------------------------------------------------
extern "C" void kernel_launch(void* const* d_in, const int* in_sizes, int n_in,
                              void* d_out, int out_size, void* d_ws, size_t ws_size,
                              hipStream_t stream) {
    const float* x  = (const float*)d_in[0];
    const float* w1 = (const float*)d_in[1];
    const float* b1 = (const float*)d_in[2];
    const float* w2 = (const float*)d_in[3];
    const float* b2 = (const float*)d_in[4];
    const float* g  = (const float*)d_in[5];
    float* out = (float*)d_out;

    char* ws = (char*)d_ws;
    float* sv   = (float*)ws;
    float* part = (float*)(ws + 256);
    u16* wq1   = (u16*)(ws + 4096);
    u16* wq2   = (u16*)(ws + 4096 + 1572864);
    u16* h_t   = (u16*)(ws + 4096 + 2 * 1572864);                 // [16][4098][512] bf16
    u16* h1_t  = (u16*)(ws + 4096 + 2 * 1572864 + 67141632);      // [16][4098][512] bf16

    hipFuncSetAttribute((const void*)conv_gemm8<1>,
                        hipFuncAttributeMaxDynamicSharedMemorySize, 73728);
    hipFuncSetAttribute((const void*)conv_gemm8<2>,
                        hipFuncAttributeMaxDynamicSharedMemorySize, 73728);

    absmean_partial<<<dim3(256), dim3(256), 0, stream>>>(w1, w2, part);
    finalize_scale<<<dim3(1), dim3(256), 0, stream>>>(part, sv);
    quantize_w<<<dim3(3072), dim3(256), 0, stream>>>(w1, sv, 0, wq1);
    quantize_w<<<dim3(3072), dim3(256), 0, stream>>>(w2, sv, 1, wq2);
    zero_pads<<<dim3(64), dim3(256), 0, stream>>>(h_t, h1_t);
    rms_silu_transpose<<<dim3(2048), dim3(256), 0, stream>>>(x, g, h_t);
    conv_gemm8<1><<<dim3(1024), dim3(256), 73728, stream>>>(h_t, wq1, sv, b1,
                                                            nullptr, h1_t, nullptr);
    conv_gemm8<2><<<dim3(1024), dim3(256), 73728, stream>>>(h1_t, wq2, sv + 1, b2,
                                                            x, nullptr, out);
}